// Round 2
// baseline (3762.066 us; speedup 1.0000x reference)
//
#include <hip/hip_runtime.h>
#include <hip/hip_bf16.h>

#define Bsz 2
#define Tsz 1024
#define Vsz 50257
#define Csz 768
#define Lsz 12
#define Hsz 12
#define Msz 2048  // B*T
#define VPAD 50304  // Vsz rounded up to 128

typedef __attribute__((ext_vector_type(8))) short short8;
typedef __attribute__((ext_vector_type(4))) float f32x4;

__device__ __forceinline__ ushort f2bf(float f) {
  union { float f; unsigned u; } v; v.f = f;
  return (ushort)((v.u + 0x7FFFu + ((v.u >> 16) & 1u)) >> 16);
}

__device__ __forceinline__ void load_lds16(const void* g, void* l) {
  __builtin_amdgcn_global_load_lds(
      (const __attribute__((address_space(1))) unsigned int*)g,
      (__attribute__((address_space(3))) unsigned int*)l, 16, 0, 0);
}

// ---------------- embedding ----------------
__global__ void k_embed(const int* __restrict__ idx, const float* __restrict__ wte,
                        const float* __restrict__ wpe, float* __restrict__ x) {
  int m = blockIdx.x;
  int t = m & (Tsz - 1);
  const float* src = wte + (size_t)idx[m] * Csz;
  const float* pe  = wpe + (size_t)t * Csz;
  float* dst = x + (size_t)m * Csz;
  for (int c = threadIdx.x; c < Csz; c += 256)
    dst[c] = src[c] + pe[c];
}

// ---------------- layernorm (f32 in -> bf16 out) ----------------
__global__ void k_ln(const float* __restrict__ x, const float* __restrict__ w,
                     const float* __restrict__ b, ushort* __restrict__ out) {
  int m = blockIdx.x;
  const float* row = x + (size_t)m * Csz;
  int tid = threadIdx.x;
  float v0 = row[tid], v1 = row[tid + 256], v2 = row[tid + 512];
  float s = v0 + v1 + v2;
  float q = v0 * v0 + v1 * v1 + v2 * v2;
  for (int o = 32; o; o >>= 1) {
    s += __shfl_down(s, o, 64);
    q += __shfl_down(q, o, 64);
  }
  __shared__ float red[8];
  __shared__ float mv[2];
  int wid = tid >> 6, lane = tid & 63;
  if (!lane) { red[wid] = s; red[4 + wid] = q; }
  __syncthreads();
  if (!tid) {
    float S = red[0] + red[1] + red[2] + red[3];
    float Q = red[4] + red[5] + red[6] + red[7];
    float mean = S * (1.0f / Csz);
    float var = Q * (1.0f / Csz) - mean * mean;
    mv[0] = mean; mv[1] = rsqrtf(var + 1e-5f);
  }
  __syncthreads();
  float mean = mv[0], rs = mv[1];
  ushort* o = out + (size_t)m * Csz;
  o[tid]       = f2bf((v0 - mean) * rs * w[tid]       + b[tid]);
  o[tid + 256] = f2bf((v1 - mean) * rs * w[tid + 256] + b[tid + 256]);
  o[tid + 512] = f2bf((v2 - mean) * rs * w[tid + 512] + b[tid + 512]);
}

// ---------------- transpose f32 [R][Cn] -> bf16 [Cn][R] ----------------
__global__ void k_transpose_bf16(const float* __restrict__ src, ushort* __restrict__ dst,
                                 int R, int Cn) {
  __shared__ float t[32][33];
  int c0 = blockIdx.x * 32, r0 = blockIdx.y * 32;
  int tx = threadIdx.x & 31, ty = threadIdx.x >> 5;  // 32 x 8
#pragma unroll
  for (int k = 0; k < 4; k++)
    t[ty + 8 * k][tx] = src[(size_t)(r0 + ty + 8 * k) * Cn + c0 + tx];
  __syncthreads();
#pragma unroll
  for (int k = 0; k < 4; k++)
    dst[(size_t)(c0 + ty + 8 * k) * R + r0 + tx] = f2bf(t[tx][ty + 8 * k]);
}

// ---------------- f32 -> bf16 elementwise with zero-padded tail ----------------
__global__ void k_f32_to_bf16_pad(const float* __restrict__ src, ushort* __restrict__ dst,
                                  int n_src, int n_tot) {
  int stride = gridDim.x * 256 * 4;
  for (int i = (blockIdx.x * 256 + threadIdx.x) * 4; i < n_tot; i += stride) {
    ushort4 o;
    if (i + 3 < n_src) {
      float4 v = *(const float4*)(src + i);
      o.x = f2bf(v.x); o.y = f2bf(v.y); o.z = f2bf(v.z); o.w = f2bf(v.w);
    } else {
      o.x = o.y = o.z = o.w = 0;
    }
    *(ushort4*)(dst + i) = o;
  }
}

// ---------------- GELU (tanh approx), f32 in -> bf16 out ----------------
__global__ void k_gelu(const float* __restrict__ src, ushort* __restrict__ dst, int n) {
  int i = (blockIdx.x * 256 + threadIdx.x) * 4;
  if (i >= n) return;
  float4 v = *(const float4*)(src + i);
  float xs[4] = {v.x, v.y, v.z, v.w};
  ushort os[4];
#pragma unroll
  for (int j = 0; j < 4; j++) {
    float xv = xs[j];
    float g = 0.5f * xv * (1.0f + tanhf(0.7978845608f * (xv + 0.044715f * xv * xv * xv)));
    os[j] = f2bf(g);
  }
  ushort4 o; o.x = os[0]; o.y = os[1]; o.z = os[2]; o.w = os[3];
  *(ushort4*)(dst + i) = o;
}

// ---------------- GEMM 128x128 (m97 structure): out[M][N] = A[M][K] @ Bt[N][K] ----------------
// 4 waves (2x2), each wave 64x64 via 4x4 mfma_f32_16x16x32_bf16 frags.
// Linear LDS (no pad) staged with global_load_lds width=16. BK=32.
// Bt must have >= n0+128 valid (padded) rows for every tile; C-write guarded by n<N.
template <bool SWZ>
__global__ __launch_bounds__(256) void k_gemm128(
    const ushort* __restrict__ A, const ushort* __restrict__ Bt,
    const float* __restrict__ bias, const float* res,
    float* __restrict__ out, int N, int K, int ntx) {
  __shared__ __align__(16) ushort As[128 * 32];
  __shared__ __align__(16) ushort Bs[128 * 32];

  int bid = blockIdx.x;
  if (SWZ) {
    int nwg = gridDim.x;
    bid = (bid & 7) * (nwg >> 3) + (bid >> 3);
  }
  int bx = bid % ntx, by = bid / ntx;
  int n0 = bx * 128, m0 = by * 128;

  int tid = threadIdx.x;
  int wid = tid >> 6, lane = tid & 63, lg = lane >> 4, lr = lane & 15;
  int wm = (wid >> 1) * 64, wn = (wid & 1) * 64;

  const f32x4 FZ = {0.f, 0.f, 0.f, 0.f};
  f32x4 acc[4][4];
#pragma unroll
  for (int i = 0; i < 4; i++)
#pragma unroll
    for (int j = 0; j < 4; j++) acc[i][j] = FZ;

  // staging map: chunk c = wid*2 + i covers LDS bytes [c*1024, c*1024+1024)
  // row = c*16 + (lane>>2), col = (lane&3)*8  (bf16 elems), row stride 32
  int srow = (lane >> 2), scol = (lane & 3) * 8;

  for (int k0 = 0; k0 < K; k0 += 32) {
#pragma unroll
    for (int i = 0; i < 2; i++) {
      int c = wid * 2 + i;
      int row = c * 16 + srow;
      load_lds16(A + (size_t)(m0 + row) * K + k0 + scol, As + c * 512);
      load_lds16(Bt + (size_t)(n0 + row) * K + k0 + scol, Bs + c * 512);
    }
    __syncthreads();

    short8 a[4], b[4];
#pragma unroll
    for (int f = 0; f < 4; f++) {
      a[f] = *(const short8*)&As[(wm + f * 16 + lr) * 32 + lg * 8];
      b[f] = *(const short8*)&Bs[(wn + f * 16 + lr) * 32 + lg * 8];
    }
#pragma unroll
    for (int fi = 0; fi < 4; fi++)
#pragma unroll
      for (int fj = 0; fj < 4; fj++)
        acc[fi][fj] = __builtin_amdgcn_mfma_f32_16x16x32_bf16(a[fi], b[fj], acc[fi][fj], 0, 0, 0);
    __syncthreads();
  }

#pragma unroll
  for (int fi = 0; fi < 4; fi++)
#pragma unroll
    for (int fj = 0; fj < 4; fj++) {
      int gn = n0 + wn + fj * 16 + lr;
      if (gn < N) {
        float bv = bias ? bias[gn] : 0.f;
#pragma unroll
        for (int i = 0; i < 4; i++) {
          int gm = m0 + wm + fi * 16 + 4 * lg + i;
          size_t o = (size_t)gm * N + gn;
          float v = acc[fi][fj][i] + bv;
          if (res) v += res[o];
          out[o] = v;
        }
      }
    }
}

// ---------------- fallback small-tile GEMM with f32 B (lm_head only, if ws too small) ----------------
__global__ void k_gemm_bt_f32(const ushort* __restrict__ A, const float* __restrict__ Bt,
                              const float* __restrict__ bias, const float* res,
                              float* out, int N, int K) {
  __shared__ __align__(16) ushort As[64 * 40];
  __shared__ __align__(16) ushort Bs[64 * 40];
  int n0 = blockIdx.x * 64, m0 = blockIdx.y * 64;
  int tid = threadIdx.x;
  int wid = tid >> 6, lane = tid & 63, lg = lane >> 4, lr = lane & 15;
  int wm = (wid >> 1) * 32, wn = (wid & 1) * 32;
  const f32x4 FZ = {0.f, 0.f, 0.f, 0.f};
  f32x4 acc[2][2];
  acc[0][0] = FZ; acc[0][1] = FZ; acc[1][0] = FZ; acc[1][1] = FZ;

  int ldr = tid >> 2, ldc = (tid & 3) * 8;
  for (int k0 = 0; k0 < K; k0 += 32) {
    *(int4*)&As[ldr * 40 + ldc] = *(const int4*)(A + (size_t)(m0 + ldr) * K + k0 + ldc);
    int n = n0 + ldr;
    uint4 pk = {0u, 0u, 0u, 0u};
    if (n < N) {
      const float* bp = Bt + (size_t)n * K + k0 + ldc;
      float4 x0 = *(const float4*)bp;
      float4 x1 = *(const float4*)(bp + 4);
      pk.x = (uint)f2bf(x0.x) | ((uint)f2bf(x0.y) << 16);
      pk.y = (uint)f2bf(x0.z) | ((uint)f2bf(x0.w) << 16);
      pk.z = (uint)f2bf(x1.x) | ((uint)f2bf(x1.y) << 16);
      pk.w = (uint)f2bf(x1.z) | ((uint)f2bf(x1.w) << 16);
    }
    *(uint4*)&Bs[ldr * 40 + ldc] = pk;
    __syncthreads();
    short8 a0 = *(const short8*)&As[(wm + lr) * 40 + lg * 8];
    short8 a1 = *(const short8*)&As[(wm + 16 + lr) * 40 + lg * 8];
    short8 b0 = *(const short8*)&Bs[(wn + lr) * 40 + lg * 8];
    short8 b1 = *(const short8*)&Bs[(wn + 16 + lr) * 40 + lg * 8];
    acc[0][0] = __builtin_amdgcn_mfma_f32_16x16x32_bf16(a0, b0, acc[0][0], 0, 0, 0);
    acc[0][1] = __builtin_amdgcn_mfma_f32_16x16x32_bf16(a0, b1, acc[0][1], 0, 0, 0);
    acc[1][0] = __builtin_amdgcn_mfma_f32_16x16x32_bf16(a1, b0, acc[1][0], 0, 0, 0);
    acc[1][1] = __builtin_amdgcn_mfma_f32_16x16x32_bf16(a1, b1, acc[1][1], 0, 0, 0);
    __syncthreads();
  }
#pragma unroll
  for (int mi = 0; mi < 2; mi++)
#pragma unroll
    for (int ni = 0; ni < 2; ni++) {
      int gn = n0 + wn + ni * 16 + lr;
      if (gn < N) {
        float bv = bias ? bias[gn] : 0.f;
#pragma unroll
        for (int i = 0; i < 4; i++) {
          int gm = m0 + wm + mi * 16 + 4 * lg + i;
          size_t o = (size_t)gm * N + gn;
          float v = acc[mi][ni][i] + bv;
          if (res) v += res[o];
          out[o] = v;
        }
      }
    }
}

// ---------------- flash attention (causal), qkv f32 -> y bf16 ----------------
__global__ void k_attn(const float* __restrict__ qkv, ushort* __restrict__ ybf) {
  __shared__ __align__(16) ushort Ks[32 * 72];
  __shared__ __align__(16) ushort Vs[64 * 40];   // transposed: [d][k]
  __shared__ __align__(16) ushort Ps[4 * 16 * 40];
  int q0 = blockIdx.x * 64;
  int bh = blockIdx.y;
  int b = bh / Hsz, h = bh % Hsz;
  int tid = threadIdx.x, wid = tid >> 6, lane = tid & 63, lg = lane >> 4, lr = lane & 15;
  const float* base = qkv + (size_t)b * Tsz * 2304;

  short8 aq[2];
  {
    int qt = q0 + wid * 16 + lr;
    const float* qp = base + (size_t)qt * 2304 + h * 64;
#pragma unroll
    for (int c = 0; c < 2; c++) {
      float4 x0 = *(const float4*)(qp + c * 32 + lg * 8);
      float4 x1 = *(const float4*)(qp + c * 32 + lg * 8 + 4);
      short8 v;
      v[0] = (short)f2bf(x0.x); v[1] = (short)f2bf(x0.y);
      v[2] = (short)f2bf(x0.z); v[3] = (short)f2bf(x0.w);
      v[4] = (short)f2bf(x1.x); v[5] = (short)f2bf(x1.y);
      v[6] = (short)f2bf(x1.z); v[7] = (short)f2bf(x1.w);
      aq[c] = v;
    }
  }

  const f32x4 FZ = {0.f, 0.f, 0.f, 0.f};
  f32x4 of[4];
  of[0] = FZ; of[1] = FZ; of[2] = FZ; of[3] = FZ;
  float mrow[4] = {-INFINITY, -INFINITY, -INFINITY, -INFINITY};
  float lrow[4] = {0.f, 0.f, 0.f, 0.f};

  int nkt = q0 / 32 + 2;
  for (int kt = 0; kt < nkt; kt++) {
    int k0 = kt * 32;
    {
      int row = tid >> 3, dblk = (tid & 7) * 8;
      const float* kp = base + (size_t)(k0 + row) * 2304 + 768 + h * 64 + dblk;
      float4 x0 = *(const float4*)kp;
      float4 x1 = *(const float4*)(kp + 4);
      uint4 pk;
      pk.x = (uint)f2bf(x0.x) | ((uint)f2bf(x0.y) << 16);
      pk.y = (uint)f2bf(x0.z) | ((uint)f2bf(x0.w) << 16);
      pk.z = (uint)f2bf(x1.x) | ((uint)f2bf(x1.y) << 16);
      pk.w = (uint)f2bf(x1.z) | ((uint)f2bf(x1.w) << 16);
      *(uint4*)&Ks[row * 72 + dblk] = pk;
      const float* vp = base + (size_t)(k0 + row) * 2304 + 1536 + h * 64 + dblk;
      float4 v0 = *(const float4*)vp;
      float4 v1 = *(const float4*)(vp + 4);
      float vv[8] = {v0.x, v0.y, v0.z, v0.w, v1.x, v1.y, v1.z, v1.w};
#pragma unroll
      for (int j = 0; j < 8; j++) Vs[(dblk + j) * 40 + row] = f2bf(vv[j]);
    }
    __syncthreads();

    f32x4 sf[2];
    sf[0] = FZ; sf[1] = FZ;
#pragma unroll
    for (int c = 0; c < 2; c++) {
#pragma unroll
      for (int nf = 0; nf < 2; nf++) {
        short8 bk = *(const short8*)&Ks[(nf * 16 + lr) * 72 + c * 32 + lg * 8];
        sf[nf] = __builtin_amdgcn_mfma_f32_16x16x32_bf16(aq[c], bk, sf[nf], 0, 0, 0);
      }
    }

    float p[2][4];
#pragma unroll
    for (int i = 0; i < 4; i++) {
      int qr = q0 + wid * 16 + 4 * lg + i;
      float s0 = sf[0][i] * 0.125f;
      float s1 = sf[1][i] * 0.125f;
      if (k0 + lr > qr) s0 = -INFINITY;
      if (k0 + 16 + lr > qr) s1 = -INFINITY;
      float rm = fmaxf(s0, s1);
#pragma unroll
      for (int o = 1; o < 16; o <<= 1) rm = fmaxf(rm, __shfl_xor(rm, o, 16));
      float mnew = fmaxf(mrow[i], rm);
      float scale = __expf(mrow[i] - mnew);
      float p0 = __expf(s0 - mnew);
      float p1 = __expf(s1 - mnew);
      float rs = p0 + p1;
#pragma unroll
      for (int o = 1; o < 16; o <<= 1) rs += __shfl_xor(rs, o, 16);
      lrow[i] = lrow[i] * scale + rs;
      mrow[i] = mnew;
      p[0][i] = p0; p[1][i] = p1;
      of[0][i] *= scale; of[1][i] *= scale; of[2][i] *= scale; of[3][i] *= scale;
    }

#pragma unroll
    for (int nf = 0; nf < 2; nf++)
#pragma unroll
      for (int i = 0; i < 4; i++)
        Ps[(wid * 16 + 4 * lg + i) * 40 + nf * 16 + lr] = f2bf(p[nf][i]);
    __syncthreads();

    short8 ap = *(const short8*)&Ps[(wid * 16 + lr) * 40 + lg * 8];
#pragma unroll
    for (int df = 0; df < 4; df++) {
      short8 bv = *(const short8*)&Vs[(df * 16 + lr) * 40 + lg * 8];
      of[df] = __builtin_amdgcn_mfma_f32_16x16x32_bf16(ap, bv, of[df], 0, 0, 0);
    }
    __syncthreads();
  }

  ushort* yp = ybf + (size_t)b * Tsz * Csz;
#pragma unroll
  for (int df = 0; df < 4; df++)
#pragma unroll
    for (int i = 0; i < 4; i++) {
      int qr = q0 + wid * 16 + 4 * lg + i;
      float v = of[df][i] / lrow[i];
      yp[(size_t)qr * Csz + h * 64 + df * 16 + lr] = f2bf(v);
    }
}

// ---------------- host ----------------
extern "C" void kernel_launch(void* const* d_in, const int* in_sizes, int n_in,
                              void* d_out, int out_size, void* d_ws, size_t ws_size,
                              hipStream_t stream) {
  (void)in_sizes; (void)n_in; (void)out_size;
  const int* idx      = (const int*)d_in[0];
  const float* wte    = (const float*)d_in[1];
  const float* wpe    = (const float*)d_in[2];
  const float* ln1_w  = (const float*)d_in[3];
  const float* ln1_b  = (const float*)d_in[4];
  const float* attn_w = (const float*)d_in[5];
  const float* attn_b = (const float*)d_in[6];
  const float* proj_w = (const float*)d_in[7];
  const float* proj_b = (const float*)d_in[8];
  const float* ln2_w  = (const float*)d_in[9];
  const float* ln2_b  = (const float*)d_in[10];
  const float* fc_w   = (const float*)d_in[11];
  const float* fc_b   = (const float*)d_in[12];
  const float* fc2_w  = (const float*)d_in[13];
  const float* fc2_b  = (const float*)d_in[14];
  const float* lnf_w  = (const float*)d_in[15];
  const float* lnf_b  = (const float*)d_in[16];
  const float* lm_w   = (const float*)d_in[17];
  float* out = (float*)d_out;

  char* ws = (char*)d_ws;
  float*  x    = (float*)(ws + 0);            // 2048*768*4   = 6291456
  float*  qkv  = (float*)(ws + 6291456);      // 2048*2304*4  = 18874368
  float*  fca  = (float*)(ws + 25165824);     // 2048*3072*4  = 25165824
  ushort* abuf = (ushort*)(ws + 50331648);    // 2048*3072*2  = 12582912
  ushort* wT   = (ushort*)(ws + 62914560);    // 3072*768*2   = 4718592
  ushort* lmw  = (ushort*)(ws + 67633152);    // 50304*768*2  = 77266944
  const size_t NEED_FULL = 67633152ull + (size_t)VPAD * Csz * 2;  // 144900096
  bool lm_bf16 = ws_size >= NEED_FULL;

  k_embed<<<Msz, 256, 0, stream>>>(idx, wte, wpe, x);
  if (lm_bf16)
    k_f32_to_bf16_pad<<<4096, 256, 0, stream>>>(lm_w, lmw, Vsz * Csz, VPAD * Csz);

  for (int l = 0; l < Lsz; l++) {
    // --- attention ---
    k_ln<<<Msz, 256, 0, stream>>>(x, ln1_w + l * Csz, ln1_b + l * Csz, abuf);
    k_transpose_bf16<<<dim3(3 * Csz / 32, Csz / 32), 256, 0, stream>>>(
        attn_w + (size_t)l * Csz * 3 * Csz, wT, Csz, 3 * Csz);
    k_gemm128<false><<<(3 * Csz / 128) * (Msz / 128), 256, 0, stream>>>(
        abuf, wT, attn_b + (size_t)l * 3 * Csz, nullptr, qkv, 3 * Csz, Csz, 3 * Csz / 128);
    k_attn<<<dim3(Tsz / 64, Bsz * Hsz), 256, 0, stream>>>(qkv, abuf);
    k_transpose_bf16<<<dim3(Csz / 32, Csz / 32), 256, 0, stream>>>(
        proj_w + (size_t)l * Csz * Csz, wT, Csz, Csz);
    k_gemm128<false><<<(Csz / 128) * (Msz / 128), 256, 0, stream>>>(
        abuf, wT, proj_b + (size_t)l * Csz, x, x, Csz, Csz, Csz / 128);
    // --- mlp ---
    k_ln<<<Msz, 256, 0, stream>>>(x, ln2_w + l * Csz, ln2_b + l * Csz, abuf);
    k_transpose_bf16<<<dim3(4 * Csz / 32, Csz / 32), 256, 0, stream>>>(
        fc_w + (size_t)l * Csz * 4 * Csz, wT, Csz, 4 * Csz);
    k_gemm128<false><<<(4 * Csz / 128) * (Msz / 128), 256, 0, stream>>>(
        abuf, wT, fc_b + (size_t)l * 4 * Csz, nullptr, fca, 4 * Csz, Csz, 4 * Csz / 128);
    k_gelu<<<(Msz * 4 * Csz) / 1024, 256, 0, stream>>>(fca, abuf, Msz * 4 * Csz);
    k_transpose_bf16<<<dim3(Csz / 32, 4 * Csz / 32), 256, 0, stream>>>(
        fc2_w + (size_t)l * 4 * Csz * Csz, wT, 4 * Csz, Csz);
    k_gemm128<false><<<(Csz / 128) * (Msz / 128), 256, 0, stream>>>(
        abuf, wT, fc2_b + (size_t)l * Csz, x, x, Csz, 4 * Csz, Csz / 128);
  }

  k_ln<<<Msz, 256, 0, stream>>>(x, lnf_w, lnf_b, abuf);
  if (lm_bf16) {
    int ntx = VPAD / 128;  // 393
    k_gemm128<true><<<ntx * (Msz / 128), 256, 0, stream>>>(
        abuf, lmw, nullptr, nullptr, out, Vsz, Csz, ntx);
  } else {
    int ntiles = (Vsz + 63) / 64;
    k_gemm_bt_f32<<<dim3(ntiles, Msz / 64), 256, 0, stream>>>(
        abuf, lm_w, nullptr, nullptr, out, Vsz, Csz);
  }
}

// Round 3
// 3004.580 us; speedup vs baseline: 1.2521x; 1.2521x over previous
//
#include <hip/hip_runtime.h>
#include <hip/hip_bf16.h>

#define Bsz 2
#define Tsz 1024
#define Vsz 50257
#define Csz 768
#define Lsz 12
#define Hsz 12
#define Msz 2048  // B*T
#define VPAD 50304  // Vsz rounded up to 128

typedef __attribute__((ext_vector_type(8))) short short8;
typedef __attribute__((ext_vector_type(4))) float f32x4;

__device__ __forceinline__ ushort f2bf(float f) {
  union { float f; unsigned u; } v; v.f = f;
  return (ushort)((v.u + 0x7FFFu + ((v.u >> 16) & 1u)) >> 16);
}

__device__ __forceinline__ void load_lds16(const void* g, void* l) {
  __builtin_amdgcn_global_load_lds(
      (const __attribute__((address_space(1))) unsigned int*)g,
      (__attribute__((address_space(3))) unsigned int*)l, 16, 0, 0);
}

// ---------------- embedding ----------------
__global__ void k_embed(const int* __restrict__ idx, const float* __restrict__ wte,
                        const float* __restrict__ wpe, float* __restrict__ x) {
  int m = blockIdx.x;
  int t = m & (Tsz - 1);
  const float* src = wte + (size_t)idx[m] * Csz;
  const float* pe  = wpe + (size_t)t * Csz;
  float* dst = x + (size_t)m * Csz;
  for (int c = threadIdx.x; c < Csz; c += 256)
    dst[c] = src[c] + pe[c];
}

// ---------------- layernorm (f32 in -> bf16 out) ----------------
__global__ void k_ln(const float* __restrict__ x, const float* __restrict__ w,
                     const float* __restrict__ b, ushort* __restrict__ out) {
  int m = blockIdx.x;
  const float* row = x + (size_t)m * Csz;
  int tid = threadIdx.x;
  float v0 = row[tid], v1 = row[tid + 256], v2 = row[tid + 512];
  float s = v0 + v1 + v2;
  float q = v0 * v0 + v1 * v1 + v2 * v2;
  for (int o = 32; o; o >>= 1) {
    s += __shfl_down(s, o, 64);
    q += __shfl_down(q, o, 64);
  }
  __shared__ float red[8];
  __shared__ float mv[2];
  int wid = tid >> 6, lane = tid & 63;
  if (!lane) { red[wid] = s; red[4 + wid] = q; }
  __syncthreads();
  if (!tid) {
    float S = red[0] + red[1] + red[2] + red[3];
    float Q = red[4] + red[5] + red[6] + red[7];
    float mean = S * (1.0f / Csz);
    float var = Q * (1.0f / Csz) - mean * mean;
    mv[0] = mean; mv[1] = rsqrtf(var + 1e-5f);
  }
  __syncthreads();
  float mean = mv[0], rs = mv[1];
  ushort* o = out + (size_t)m * Csz;
  o[tid]       = f2bf((v0 - mean) * rs * w[tid]       + b[tid]);
  o[tid + 256] = f2bf((v1 - mean) * rs * w[tid + 256] + b[tid + 256]);
  o[tid + 512] = f2bf((v2 - mean) * rs * w[tid + 512] + b[tid + 512]);
}

// ---------------- transpose f32 [R][Cn] -> bf16 [Cn][R] ----------------
__global__ void k_transpose_bf16(const float* __restrict__ src, ushort* __restrict__ dst,
                                 int R, int Cn) {
  __shared__ float t[32][33];
  int c0 = blockIdx.x * 32, r0 = blockIdx.y * 32;
  int tx = threadIdx.x & 31, ty = threadIdx.x >> 5;  // 32 x 8
#pragma unroll
  for (int k = 0; k < 4; k++)
    t[ty + 8 * k][tx] = src[(size_t)(r0 + ty + 8 * k) * Cn + c0 + tx];
  __syncthreads();
#pragma unroll
  for (int k = 0; k < 4; k++)
    dst[(size_t)(c0 + ty + 8 * k) * R + r0 + tx] = f2bf(t[tx][ty + 8 * k]);
}

// ---------------- f32 -> bf16 elementwise with zero-padded tail ----------------
__global__ void k_f32_to_bf16_pad(const float* __restrict__ src, ushort* __restrict__ dst,
                                  int n_src, int n_tot) {
  int stride = gridDim.x * 256 * 4;
  for (int i = (blockIdx.x * 256 + threadIdx.x) * 4; i < n_tot; i += stride) {
    ushort4 o;
    if (i + 3 < n_src) {
      float4 v = *(const float4*)(src + i);
      o.x = f2bf(v.x); o.y = f2bf(v.y); o.z = f2bf(v.z); o.w = f2bf(v.w);
    } else {
      o.x = o.y = o.z = o.w = 0;
    }
    *(ushort4*)(dst + i) = o;
  }
}

// ---------------- GELU (tanh approx), f32 in -> bf16 out ----------------
__global__ void k_gelu(const float* __restrict__ src, ushort* __restrict__ dst, int n) {
  int i = (blockIdx.x * 256 + threadIdx.x) * 4;
  if (i >= n) return;
  float4 v = *(const float4*)(src + i);
  float xs[4] = {v.x, v.y, v.z, v.w};
  ushort os[4];
#pragma unroll
  for (int j = 0; j < 4; j++) {
    float xv = xs[j];
    float g = 0.5f * xv * (1.0f + tanhf(0.7978845608f * (xv + 0.044715f * xv * xv * xv)));
    os[j] = f2bf(g);
  }
  ushort4 o; o.x = os[0]; o.y = os[1]; o.z = os[2]; o.w = os[3];
  *(ushort4*)(dst + i) = o;
}

// ---------------- templated GEMM: out[M][N] = A[M][K]bf16 @ Bt[N][K]bf16 (+bias,+res) ----------------
// 4 waves arranged 2x2; wave tile (FM*16)x(FN*16); BM=2*FM*16, BN=2*FN*16; BK=32.
// Linear LDS staged via global_load_lds width=16. m-fastest block mapping.
// Bt must have >= n0+BN readable rows (pad weights); C-write guarded by gn<N.
template <int BM, int BN, int FM, int FN, bool SWZ>
__global__ __launch_bounds__(256) void k_gemm(
    const ushort* __restrict__ A, const ushort* __restrict__ Bt,
    const float* __restrict__ bias, const float* res,
    float* __restrict__ out, int N, int K, int ntm) {
  __shared__ __align__(16) ushort As[BM * 32];
  __shared__ __align__(16) ushort Bs[BN * 32];

  int bid = blockIdx.x;
  if (SWZ) {
    int nwg = gridDim.x;
    bid = (bid & 7) * (nwg >> 3) + (bid >> 3);
  }
  int by = bid % ntm, bx = bid / ntm;  // m fastest: consecutive blocks share B-tile
  int m0 = by * BM, n0 = bx * BN;

  int tid = threadIdx.x;
  int wid = tid >> 6, lane = tid & 63, lg = lane >> 4, lr = lane & 15;
  int wm = (wid >> 1) * (FM * 16), wn = (wid & 1) * (FN * 16);

  const f32x4 FZ = {0.f, 0.f, 0.f, 0.f};
  f32x4 acc[FM][FN];
#pragma unroll
  for (int i = 0; i < FM; i++)
#pragma unroll
    for (int j = 0; j < FN; j++) acc[i][j] = FZ;

  // staging: chunk c covers 1024 B = 16 rows x 32 bf16; wave-uniform chunk id.
  constexpr int NCHA = BM / 16, NCH = (BM + BN) / 16, CPW = NCH / 4;
  int srow = lane >> 2, scol = (lane & 3) * 8;

  for (int k0 = 0; k0 < K; k0 += 32) {
#pragma unroll
    for (int i = 0; i < CPW; i++) {
      int c = wid * CPW + i;
      if (c < NCHA) {
        load_lds16(A + (size_t)(m0 + c * 16 + srow) * K + k0 + scol, As + c * 512);
      } else {
        int cb = c - NCHA;
        load_lds16(Bt + (size_t)(n0 + cb * 16 + srow) * K + k0 + scol, Bs + cb * 512);
      }
    }
    __syncthreads();

    short8 a[FM], b[FN];
#pragma unroll
    for (int f = 0; f < FM; f++)
      a[f] = *(const short8*)&As[(wm + f * 16 + lr) * 32 + lg * 8];
#pragma unroll
    for (int f = 0; f < FN; f++)
      b[f] = *(const short8*)&Bs[(wn + f * 16 + lr) * 32 + lg * 8];
#pragma unroll
    for (int fi = 0; fi < FM; fi++)
#pragma unroll
      for (int fj = 0; fj < FN; fj++)
        acc[fi][fj] = __builtin_amdgcn_mfma_f32_16x16x32_bf16(a[fi], b[fj], acc[fi][fj], 0, 0, 0);
    __syncthreads();
  }

#pragma unroll
  for (int fi = 0; fi < FM; fi++)
#pragma unroll
    for (int fj = 0; fj < FN; fj++) {
      int gn = n0 + wn + fj * 16 + lr;
      if (gn < N) {
        float bv = bias ? bias[gn] : 0.f;
#pragma unroll
        for (int i = 0; i < 4; i++) {
          int gm = m0 + wm + fi * 16 + 4 * lg + i;
          size_t o = (size_t)gm * N + gn;
          float v = acc[fi][fj][i] + bv;
          if (res) v += res[o];
          out[o] = v;
        }
      }
    }
}

// ---------------- fallback small-tile GEMM with f32 B (lm_head only, if ws too small) ----------------
__global__ void k_gemm_bt_f32(const ushort* __restrict__ A, const float* __restrict__ Bt,
                              const float* __restrict__ bias, const float* res,
                              float* out, int N, int K) {
  __shared__ __align__(16) ushort As[64 * 40];
  __shared__ __align__(16) ushort Bs[64 * 40];
  int n0 = blockIdx.x * 64, m0 = blockIdx.y * 64;
  int tid = threadIdx.x;
  int wid = tid >> 6, lane = tid & 63, lg = lane >> 4, lr = lane & 15;
  int wm = (wid >> 1) * 32, wn = (wid & 1) * 32;
  const f32x4 FZ = {0.f, 0.f, 0.f, 0.f};
  f32x4 acc[2][2];
  acc[0][0] = FZ; acc[0][1] = FZ; acc[1][0] = FZ; acc[1][1] = FZ;

  int ldr = tid >> 2, ldc = (tid & 3) * 8;
  for (int k0 = 0; k0 < K; k0 += 32) {
    *(int4*)&As[ldr * 40 + ldc] = *(const int4*)(A + (size_t)(m0 + ldr) * K + k0 + ldc);
    int n = n0 + ldr;
    uint4 pk = {0u, 0u, 0u, 0u};
    if (n < N) {
      const float* bp = Bt + (size_t)n * K + k0 + ldc;
      float4 x0 = *(const float4*)bp;
      float4 x1 = *(const float4*)(bp + 4);
      pk.x = (uint)f2bf(x0.x) | ((uint)f2bf(x0.y) << 16);
      pk.y = (uint)f2bf(x0.z) | ((uint)f2bf(x0.w) << 16);
      pk.z = (uint)f2bf(x1.x) | ((uint)f2bf(x1.y) << 16);
      pk.w = (uint)f2bf(x1.z) | ((uint)f2bf(x1.w) << 16);
    }
    *(uint4*)&Bs[ldr * 40 + ldc] = pk;
    __syncthreads();
    short8 a0 = *(const short8*)&As[(wm + lr) * 40 + lg * 8];
    short8 a1 = *(const short8*)&As[(wm + 16 + lr) * 40 + lg * 8];
    short8 b0 = *(const short8*)&Bs[(wn + lr) * 40 + lg * 8];
    short8 b1 = *(const short8*)&Bs[(wn + 16 + lr) * 40 + lg * 8];
    acc[0][0] = __builtin_amdgcn_mfma_f32_16x16x32_bf16(a0, b0, acc[0][0], 0, 0, 0);
    acc[0][1] = __builtin_amdgcn_mfma_f32_16x16x32_bf16(a0, b1, acc[0][1], 0, 0, 0);
    acc[1][0] = __builtin_amdgcn_mfma_f32_16x16x32_bf16(a1, b0, acc[1][0], 0, 0, 0);
    acc[1][1] = __builtin_amdgcn_mfma_f32_16x16x32_bf16(a1, b1, acc[1][1], 0, 0, 0);
    __syncthreads();
  }
#pragma unroll
  for (int mi = 0; mi < 2; mi++)
#pragma unroll
    for (int ni = 0; ni < 2; ni++) {
      int gn = n0 + wn + ni * 16 + lr;
      if (gn < N) {
        float bv = bias ? bias[gn] : 0.f;
#pragma unroll
        for (int i = 0; i < 4; i++) {
          int gm = m0 + wm + mi * 16 + 4 * lg + i;
          size_t o = (size_t)gm * N + gn;
          float v = acc[mi][ni][i] + bv;
          if (res) v += res[o];
          out[o] = v;
        }
      }
    }
}

// ---------------- flash attention (causal), qkv f32 -> y bf16 ----------------
__global__ void k_attn(const float* __restrict__ qkv, ushort* __restrict__ ybf) {
  __shared__ __align__(16) ushort Ks[32 * 72];
  __shared__ __align__(16) ushort Vs[64 * 40];   // transposed: [d][k]
  __shared__ __align__(16) ushort Ps[4 * 16 * 40];
  int q0 = blockIdx.x * 64;
  int bh = blockIdx.y;
  int b = bh / Hsz, h = bh % Hsz;
  int tid = threadIdx.x, wid = tid >> 6, lane = tid & 63, lg = lane >> 4, lr = lane & 15;
  const float* base = qkv + (size_t)b * Tsz * 2304;

  short8 aq[2];
  {
    int qt = q0 + wid * 16 + lr;
    const float* qp = base + (size_t)qt * 2304 + h * 64;
#pragma unroll
    for (int c = 0; c < 2; c++) {
      float4 x0 = *(const float4*)(qp + c * 32 + lg * 8);
      float4 x1 = *(const float4*)(qp + c * 32 + lg * 8 + 4);
      short8 v;
      v[0] = (short)f2bf(x0.x); v[1] = (short)f2bf(x0.y);
      v[2] = (short)f2bf(x0.z); v[3] = (short)f2bf(x0.w);
      v[4] = (short)f2bf(x1.x); v[5] = (short)f2bf(x1.y);
      v[6] = (short)f2bf(x1.z); v[7] = (short)f2bf(x1.w);
      aq[c] = v;
    }
  }

  const f32x4 FZ = {0.f, 0.f, 0.f, 0.f};
  f32x4 of[4];
  of[0] = FZ; of[1] = FZ; of[2] = FZ; of[3] = FZ;
  float mrow[4] = {-INFINITY, -INFINITY, -INFINITY, -INFINITY};
  float lrow[4] = {0.f, 0.f, 0.f, 0.f};

  int nkt = q0 / 32 + 2;
  for (int kt = 0; kt < nkt; kt++) {
    int k0 = kt * 32;
    {
      int row = tid >> 3, dblk = (tid & 7) * 8;
      const float* kp = base + (size_t)(k0 + row) * 2304 + 768 + h * 64 + dblk;
      float4 x0 = *(const float4*)kp;
      float4 x1 = *(const float4*)(kp + 4);
      uint4 pk;
      pk.x = (uint)f2bf(x0.x) | ((uint)f2bf(x0.y) << 16);
      pk.y = (uint)f2bf(x0.z) | ((uint)f2bf(x0.w) << 16);
      pk.z = (uint)f2bf(x1.x) | ((uint)f2bf(x1.y) << 16);
      pk.w = (uint)f2bf(x1.z) | ((uint)f2bf(x1.w) << 16);
      *(uint4*)&Ks[row * 72 + dblk] = pk;
      const float* vp = base + (size_t)(k0 + row) * 2304 + 1536 + h * 64 + dblk;
      float4 v0 = *(const float4*)vp;
      float4 v1 = *(const float4*)(vp + 4);
      float vv[8] = {v0.x, v0.y, v0.z, v0.w, v1.x, v1.y, v1.z, v1.w};
#pragma unroll
      for (int j = 0; j < 8; j++) Vs[(dblk + j) * 40 + row] = f2bf(vv[j]);
    }
    __syncthreads();

    f32x4 sf[2];
    sf[0] = FZ; sf[1] = FZ;
#pragma unroll
    for (int c = 0; c < 2; c++) {
#pragma unroll
      for (int nf = 0; nf < 2; nf++) {
        short8 bk = *(const short8*)&Ks[(nf * 16 + lr) * 72 + c * 32 + lg * 8];
        sf[nf] = __builtin_amdgcn_mfma_f32_16x16x32_bf16(aq[c], bk, sf[nf], 0, 0, 0);
      }
    }

    float p[2][4];
#pragma unroll
    for (int i = 0; i < 4; i++) {
      int qr = q0 + wid * 16 + 4 * lg + i;
      float s0 = sf[0][i] * 0.125f;
      float s1 = sf[1][i] * 0.125f;
      if (k0 + lr > qr) s0 = -INFINITY;
      if (k0 + 16 + lr > qr) s1 = -INFINITY;
      float rm = fmaxf(s0, s1);
#pragma unroll
      for (int o = 1; o < 16; o <<= 1) rm = fmaxf(rm, __shfl_xor(rm, o, 16));
      float mnew = fmaxf(mrow[i], rm);
      float scale = __expf(mrow[i] - mnew);
      float p0 = __expf(s0 - mnew);
      float p1 = __expf(s1 - mnew);
      float rs = p0 + p1;
#pragma unroll
      for (int o = 1; o < 16; o <<= 1) rs += __shfl_xor(rs, o, 16);
      lrow[i] = lrow[i] * scale + rs;
      mrow[i] = mnew;
      p[0][i] = p0; p[1][i] = p1;
      of[0][i] *= scale; of[1][i] *= scale; of[2][i] *= scale; of[3][i] *= scale;
    }

#pragma unroll
    for (int nf = 0; nf < 2; nf++)
#pragma unroll
      for (int i = 0; i < 4; i++)
        Ps[(wid * 16 + 4 * lg + i) * 40 + nf * 16 + lr] = f2bf(p[nf][i]);
    __syncthreads();

    short8 ap = *(const short8*)&Ps[(wid * 16 + lr) * 40 + lg * 8];
#pragma unroll
    for (int df = 0; df < 4; df++) {
      short8 bv = *(const short8*)&Vs[(df * 16 + lr) * 40 + lg * 8];
      of[df] = __builtin_amdgcn_mfma_f32_16x16x32_bf16(ap, bv, of[df], 0, 0, 0);
    }
    __syncthreads();
  }

  ushort* yp = ybf + (size_t)b * Tsz * Csz;
#pragma unroll
  for (int df = 0; df < 4; df++)
#pragma unroll
    for (int i = 0; i < 4; i++) {
      int qr = q0 + wid * 16 + 4 * lg + i;
      float v = of[df][i] / lrow[i];
      yp[(size_t)qr * Csz + h * 64 + df * 16 + lr] = f2bf(v);
    }
}

// ---------------- host ----------------
extern "C" void kernel_launch(void* const* d_in, const int* in_sizes, int n_in,
                              void* d_out, int out_size, void* d_ws, size_t ws_size,
                              hipStream_t stream) {
  (void)in_sizes; (void)n_in; (void)out_size;
  const int* idx      = (const int*)d_in[0];
  const float* wte    = (const float*)d_in[1];
  const float* wpe    = (const float*)d_in[2];
  const float* ln1_w  = (const float*)d_in[3];
  const float* ln1_b  = (const float*)d_in[4];
  const float* attn_w = (const float*)d_in[5];
  const float* attn_b = (const float*)d_in[6];
  const float* proj_w = (const float*)d_in[7];
  const float* proj_b = (const float*)d_in[8];
  const float* ln2_w  = (const float*)d_in[9];
  const float* ln2_b  = (const float*)d_in[10];
  const float* fc_w   = (const float*)d_in[11];
  const float* fc_b   = (const float*)d_in[12];
  const float* fc2_w  = (const float*)d_in[13];
  const float* fc2_b  = (const float*)d_in[14];
  const float* lnf_w  = (const float*)d_in[15];
  const float* lnf_b  = (const float*)d_in[16];
  const float* lm_w   = (const float*)d_in[17];
  float* out = (float*)d_out;

  char* ws = (char*)d_ws;
  float*  x    = (float*)(ws + 0);            // 2048*768*4   = 6291456
  float*  qkv  = (float*)(ws + 6291456);      // 2048*2304*4  = 18874368
  float*  fca  = (float*)(ws + 25165824);     // 2048*3072*4  = 25165824
  ushort* abuf = (ushort*)(ws + 50331648);    // 2048*3072*2  = 12582912
  ushort* wT   = (ushort*)(ws + 62914560);    // 3072*768*2   = 4718592
  ushort* lmw  = (ushort*)(ws + 67633152);    // 50304*768*2  = 77266944
  const size_t NEED_FULL = 67633152ull + (size_t)VPAD * Csz * 2;  // 144900096
  bool lm_bf16 = ws_size >= NEED_FULL;

  k_embed<<<Msz, 256, 0, stream>>>(idx, wte, wpe, x);
  if (lm_bf16)
    k_f32_to_bf16_pad<<<4096, 256, 0, stream>>>(lm_w, lmw, Vsz * Csz, VPAD * Csz);

  for (int l = 0; l < Lsz; l++) {
    // --- attention ---
    k_ln<<<Msz, 256, 0, stream>>>(x, ln1_w + l * Csz, ln1_b + l * Csz, abuf);
    k_transpose_bf16<<<dim3(3 * Csz / 32, Csz / 32), 256, 0, stream>>>(
        attn_w + (size_t)l * Csz * 3 * Csz, wT, Csz, 3 * Csz);
    k_gemm<64, 128, 2, 4, false><<<(Msz / 64) * (3 * Csz / 128), 256, 0, stream>>>(
        abuf, wT, attn_b + (size_t)l * 3 * Csz, nullptr, qkv, 3 * Csz, Csz, Msz / 64);
    k_attn<<<dim3(Tsz / 64, Bsz * Hsz), 256, 0, stream>>>(qkv, abuf);
    k_transpose_bf16<<<dim3(Csz / 32, Csz / 32), 256, 0, stream>>>(
        proj_w + (size_t)l * Csz * Csz, wT, Csz, Csz);
    k_gemm<64, 64, 2, 2, false><<<(Msz / 64) * (Csz / 64), 256, 0, stream>>>(
        abuf, wT, proj_b + (size_t)l * Csz, x, x, Csz, Csz, Msz / 64);
    // --- mlp ---
    k_ln<<<Msz, 256, 0, stream>>>(x, ln2_w + l * Csz, ln2_b + l * Csz, abuf);
    k_transpose_bf16<<<dim3(4 * Csz / 32, Csz / 32), 256, 0, stream>>>(
        fc_w + (size_t)l * Csz * 4 * Csz, wT, Csz, 4 * Csz);
    k_gemm<64, 128, 2, 4, false><<<(Msz / 64) * (4 * Csz / 128), 256, 0, stream>>>(
        abuf, wT, fc_b + (size_t)l * 4 * Csz, nullptr, fca, 4 * Csz, Csz, Msz / 64);
    k_gelu<<<(Msz * 4 * Csz) / 1024, 256, 0, stream>>>(fca, abuf, Msz * 4 * Csz);
    k_transpose_bf16<<<dim3(Csz / 32, 4 * Csz / 32), 256, 0, stream>>>(
        fc2_w + (size_t)l * 4 * Csz * Csz, wT, 4 * Csz, Csz);
    k_gemm<64, 64, 2, 2, false><<<(Msz / 64) * (Csz / 64), 256, 0, stream>>>(
        abuf, wT, fc2_b + (size_t)l * Csz, x, x, Csz, 4 * Csz, Msz / 64);
  }

  k_ln<<<Msz, 256, 0, stream>>>(x, lnf_w, lnf_b, abuf);
  if (lm_bf16) {
    int ntm = Msz / 128;  // 16, m fastest
    k_gemm<128, 128, 4, 4, true><<<ntm * (VPAD / 128), 256, 0, stream>>>(
        abuf, lmw, nullptr, nullptr, out, Vsz, Csz, ntm);
  } else {
    int ntiles = (Vsz + 63) / 64;
    k_gemm_bt_f32<<<dim3(ntiles, Msz / 64), 256, 0, stream>>>(
        abuf, lm_w, nullptr, nullptr, out, Vsz, Csz);
  }
}

// Round 5
// 2958.583 us; speedup vs baseline: 1.2716x; 1.0155x over previous
//
#include <hip/hip_runtime.h>
#include <hip/hip_bf16.h>

#define Bsz 2
#define Tsz 1024
#define Vsz 50257
#define Csz 768
#define Lsz 12
#define Hsz 12
#define Msz 2048  // B*T
#define VPAD 50304  // Vsz rounded up to 128

typedef __attribute__((ext_vector_type(8))) short short8;
typedef __attribute__((ext_vector_type(4))) float f32x4;

__device__ __forceinline__ ushort f2bf(float f) {
  union { float f; unsigned u; } v; v.f = f;
  return (ushort)((v.u + 0x7FFFu + ((v.u >> 16) & 1u)) >> 16);
}

__device__ __forceinline__ void load_lds16(const void* g, void* l) {
  __builtin_amdgcn_global_load_lds(
      (const __attribute__((address_space(1))) unsigned int*)g,
      (__attribute__((address_space(3))) unsigned int*)l, 16, 0, 0);
}

// ---------------- embedding ----------------
__global__ void k_embed(const int* __restrict__ idx, const float* __restrict__ wte,
                        const float* __restrict__ wpe, float* __restrict__ x) {
  int m = blockIdx.x;
  int t = m & (Tsz - 1);
  const float* src = wte + (size_t)idx[m] * Csz;
  const float* pe  = wpe + (size_t)t * Csz;
  float* dst = x + (size_t)m * Csz;
  for (int c = threadIdx.x; c < Csz; c += 256)
    dst[c] = src[c] + pe[c];
}

// ---------------- layernorm (f32 in -> bf16 out) ----------------
__global__ void k_ln(const float* __restrict__ x, const float* __restrict__ w,
                     const float* __restrict__ b, ushort* __restrict__ out) {
  int m = blockIdx.x;
  const float* row = x + (size_t)m * Csz;
  int tid = threadIdx.x;
  float v0 = row[tid], v1 = row[tid + 256], v2 = row[tid + 512];
  float s = v0 + v1 + v2;
  float q = v0 * v0 + v1 * v1 + v2 * v2;
  for (int o = 32; o; o >>= 1) {
    s += __shfl_down(s, o, 64);
    q += __shfl_down(q, o, 64);
  }
  __shared__ float red[8];
  __shared__ float mv[2];
  int wid = tid >> 6, lane = tid & 63;
  if (!lane) { red[wid] = s; red[4 + wid] = q; }
  __syncthreads();
  if (!tid) {
    float S = red[0] + red[1] + red[2] + red[3];
    float Q = red[4] + red[5] + red[6] + red[7];
    float mean = S * (1.0f / Csz);
    float var = Q * (1.0f / Csz) - mean * mean;
    mv[0] = mean; mv[1] = rsqrtf(var + 1e-5f);
  }
  __syncthreads();
  float mean = mv[0], rs = mv[1];
  ushort* o = out + (size_t)m * Csz;
  o[tid]       = f2bf((v0 - mean) * rs * w[tid]       + b[tid]);
  o[tid + 256] = f2bf((v1 - mean) * rs * w[tid + 256] + b[tid + 256]);
  o[tid + 512] = f2bf((v2 - mean) * rs * w[tid + 512] + b[tid + 512]);
}

// ---------------- batched weight prep: transpose f32 [R][Cn] -> bf16 [Cn][R] ----------------
// Per layer tile ranges: attn_w 1728, proj_w 576, fc_w 2304, fc2_w 2304 (total 6912).
__global__ void k_prep(const float* __restrict__ aw, const float* __restrict__ pw,
                       const float* __restrict__ fw, const float* __restrict__ f2w,
                       ushort* __restrict__ wT, int l0, size_t lstride) {
  int t = blockIdx.x;
  int ly = l0 + blockIdx.y;
  const float* src; int R, Cn; size_t doff;
  if (t < 1728)      { src = aw  + (size_t)ly * Csz * 3 * Csz; R = Csz;     Cn = 3 * Csz; doff = 0; }
  else if (t < 2304) { t -= 1728; src = pw  + (size_t)ly * Csz * Csz;     R = Csz;     Cn = Csz;     doff = (size_t)3 * Csz * Csz; }
  else if (t < 4608) { t -= 2304; src = fw  + (size_t)ly * Csz * 4 * Csz; R = Csz;     Cn = 4 * Csz; doff = (size_t)4 * Csz * Csz; }
  else               { t -= 4608; src = f2w + (size_t)ly * 4 * Csz * Csz; R = 4 * Csz; Cn = Csz;     doff = (size_t)8 * Csz * Csz; }
  ushort* dst = wT + (size_t)blockIdx.y * lstride + doff;

  __shared__ float tb[32][33];
  int ncx = Cn / 32;
  int c0 = (t % ncx) * 32, r0 = (t / ncx) * 32;
  int tx = threadIdx.x & 31, ty = threadIdx.x >> 5;  // 32 x 8
#pragma unroll
  for (int k = 0; k < 4; k++)
    tb[ty + 8 * k][tx] = src[(size_t)(r0 + ty + 8 * k) * Cn + c0 + tx];
  __syncthreads();
#pragma unroll
  for (int k = 0; k < 4; k++)
    dst[(size_t)(c0 + ty + 8 * k) * R + r0 + tx] = f2bf(tb[tx][ty + 8 * k]);
}

// ---------------- f32 -> bf16 elementwise with zero-padded tail ----------------
__global__ void k_f32_to_bf16_pad(const float* __restrict__ src, ushort* __restrict__ dst,
                                  int n_src, int n_tot) {
  int stride = gridDim.x * 256 * 4;
  for (int i = (blockIdx.x * 256 + threadIdx.x) * 4; i < n_tot; i += stride) {
    ushort4 o;
    if (i + 3 < n_src) {
      float4 v = *(const float4*)(src + i);
      o.x = f2bf(v.x); o.y = f2bf(v.y); o.z = f2bf(v.z); o.w = f2bf(v.w);
    } else {
      o.x = o.y = o.z = o.w = 0;
    }
    *(ushort4*)(dst + i) = o;
  }
}

// ---------------- templated GEMM: out[M][N] = A[M][K]bf16 @ Bt[N][K]bf16 ----------------
// OUT=0: f32 +bias +res; OUT=1: bf16 +bias; OUT=2: bf16 gelu(acc+bias).
// NOTE: outv must NOT alias A (blocks read A while others write out).
// 4 waves 2x2; wave tile (FM*16)x(FN*16); BK=32; linear LDS via global_load_lds w=16.
// m-fastest block mapping; Bt must have n0+BN readable rows; C-write guarded gn<N.
template <int BM, int BN, int FM, int FN, int OUT, bool SWZ>
__global__ __launch_bounds__(256) void k_gemm(
    const ushort* __restrict__ A, const ushort* __restrict__ Bt,
    const float* __restrict__ bias, const float* res,
    void* __restrict__ outv, int N, int K, int ntm) {
  __shared__ __align__(16) ushort As[BM * 32];
  __shared__ __align__(16) ushort Bs[BN * 32];

  int bid = blockIdx.x;
  if (SWZ) {
    int nwg = gridDim.x;
    bid = (bid & 7) * (nwg >> 3) + (bid >> 3);
  }
  int by = bid % ntm, bx = bid / ntm;  // m fastest: consecutive blocks share B-tile
  int m0 = by * BM, n0 = bx * BN;

  int tid = threadIdx.x;
  int wid = tid >> 6, lane = tid & 63, lg = lane >> 4, lr = lane & 15;
  int wm = (wid >> 1) * (FM * 16), wn = (wid & 1) * (FN * 16);

  const f32x4 FZ = {0.f, 0.f, 0.f, 0.f};
  f32x4 acc[FM][FN];
#pragma unroll
  for (int i = 0; i < FM; i++)
#pragma unroll
    for (int j = 0; j < FN; j++) acc[i][j] = FZ;

  constexpr int NCHA = BM / 16, NCH = (BM + BN) / 16, CPW = NCH / 4;
  int srow = lane >> 2, scol = (lane & 3) * 8;

  for (int k0 = 0; k0 < K; k0 += 32) {
#pragma unroll
    for (int i = 0; i < CPW; i++) {
      int c = wid * CPW + i;
      if (c < NCHA) {
        load_lds16(A + (size_t)(m0 + c * 16 + srow) * K + k0 + scol, As + c * 512);
      } else {
        int cb = c - NCHA;
        load_lds16(Bt + (size_t)(n0 + cb * 16 + srow) * K + k0 + scol, Bs + cb * 512);
      }
    }
    __syncthreads();

    short8 a[FM], b[FN];
#pragma unroll
    for (int f = 0; f < FM; f++)
      a[f] = *(const short8*)&As[(wm + f * 16 + lr) * 32 + lg * 8];
#pragma unroll
    for (int f = 0; f < FN; f++)
      b[f] = *(const short8*)&Bs[(wn + f * 16 + lr) * 32 + lg * 8];
#pragma unroll
    for (int fi = 0; fi < FM; fi++)
#pragma unroll
      for (int fj = 0; fj < FN; fj++)
        acc[fi][fj] = __builtin_amdgcn_mfma_f32_16x16x32_bf16(a[fi], b[fj], acc[fi][fj], 0, 0, 0);
    __syncthreads();
  }

#pragma unroll
  for (int fi = 0; fi < FM; fi++)
#pragma unroll
    for (int fj = 0; fj < FN; fj++) {
      int gn = n0 + wn + fj * 16 + lr;
      if (gn < N) {
        float bv = bias ? bias[gn] : 0.f;
#pragma unroll
        for (int i = 0; i < 4; i++) {
          int gm = m0 + wm + fi * 16 + 4 * lg + i;
          size_t o = (size_t)gm * N + gn;
          float v = acc[fi][fj][i] + bv;
          if (OUT == 0) {
            if (res) v += res[o];
            ((float*)outv)[o] = v;
          } else if (OUT == 1) {
            ((ushort*)outv)[o] = f2bf(v);
          } else {
            float u = 0.7978845608f * (v + 0.044715f * v * v * v);
            float t = __expf(2.f * u);
            float th = 1.f - 2.f / (t + 1.f);
            ((ushort*)outv)[o] = f2bf(0.5f * v * (1.f + th));
          }
        }
      }
    }
}

// ---------------- flash attention (causal), qkv bf16 -> y bf16 ----------------
// grid (T/64, B*H); 4 waves; wave = 16 q rows; KVBLK=64.
__global__ __launch_bounds__(256) void k_attn(const ushort* __restrict__ qkv,
                                              ushort* __restrict__ ybf) {
  __shared__ __align__(16) ushort Ks[64 * 72];
  __shared__ __align__(16) ushort Vs[64 * 72];   // transposed: [d][k]
  __shared__ __align__(16) ushort Ps[4 * 16 * 72];
  int q0 = blockIdx.x * 64;
  int bh = blockIdx.y;
  int b = bh / Hsz, h = bh % Hsz;
  int tid = threadIdx.x, wid = tid >> 6, lane = tid & 63, lg = lane >> 4, lr = lane & 15;
  const ushort* base = qkv + (size_t)b * Tsz * 2304;

  // Q A-frags: row = lr, k(d) = c*32 + lg*8 + i  (direct bf16 loads)
  int qt = q0 + wid * 16 + lr;
  const ushort* qp = base + (size_t)qt * 2304 + h * 64;
  short8 aq0 = *(const short8*)(qp + lg * 8);
  short8 aq1 = *(const short8*)(qp + 32 + lg * 8);

  const f32x4 FZ = {0.f, 0.f, 0.f, 0.f};
  f32x4 of[4];
  of[0] = FZ; of[1] = FZ; of[2] = FZ; of[3] = FZ;
  float mrow[4] = {-INFINITY, -INFINITY, -INFINITY, -INFINITY};
  float lrow[4] = {0.f, 0.f, 0.f, 0.f};

  int nkt = q0 / 64 + 1;
  for (int kt = 0; kt < nkt; kt++) {
    int k0 = kt * 64;
    // stage K row-major, V transposed (bf16 copies)
#pragma unroll
    for (int r = 0; r < 2; r++) {
      int c = tid + r * 256;
      int row = c >> 3, off = (c & 7) * 8;
      *(short8*)&Ks[row * 72 + off] =
          *(const short8*)(base + (size_t)(k0 + row) * 2304 + 768 + h * 64 + off);
      short8 vv = *(const short8*)(base + (size_t)(k0 + row) * 2304 + 1536 + h * 64 + off);
#pragma unroll
      for (int j = 0; j < 8; j++) Vs[(off + j) * 72 + row] = (ushort)vv[j];
    }
    __syncthreads();

    // S = Q K^T : 16 rows x 64 keys per wave
    f32x4 sf[4];
    sf[0] = FZ; sf[1] = FZ; sf[2] = FZ; sf[3] = FZ;
#pragma unroll
    for (int nf = 0; nf < 4; nf++) {
      short8 b0 = *(const short8*)&Ks[(nf * 16 + lr) * 72 + lg * 8];
      short8 b1 = *(const short8*)&Ks[(nf * 16 + lr) * 72 + 32 + lg * 8];
      sf[nf] = __builtin_amdgcn_mfma_f32_16x16x32_bf16(aq0, b0, sf[nf], 0, 0, 0);
      sf[nf] = __builtin_amdgcn_mfma_f32_16x16x32_bf16(aq1, b1, sf[nf], 0, 0, 0);
    }

    bool last = (kt == nkt - 1);
#pragma unroll
    for (int i = 0; i < 4; i++) {
      int qr = q0 + wid * 16 + 4 * lg + i;
      float s[4];
#pragma unroll
      for (int nf = 0; nf < 4; nf++) {
        s[nf] = sf[nf][i] * 0.125f;
        if (last && k0 + nf * 16 + lr > qr) s[nf] = -INFINITY;
      }
      float rm = fmaxf(fmaxf(s[0], s[1]), fmaxf(s[2], s[3]));
#pragma unroll
      for (int o = 1; o < 16; o <<= 1) rm = fmaxf(rm, __shfl_xor(rm, o, 16));
      float mnew = fmaxf(mrow[i], rm);
      float scale = __expf(mrow[i] - mnew);
      float rs = 0.f;
#pragma unroll
      for (int nf = 0; nf < 4; nf++) {
        float p = __expf(s[nf] - mnew);
        rs += p;
        Ps[(wid * 16 + 4 * lg + i) * 72 + nf * 16 + lr] = f2bf(p);
      }
#pragma unroll
      for (int o = 1; o < 16; o <<= 1) rs += __shfl_xor(rs, o, 16);
      lrow[i] = lrow[i] * scale + rs;
      mrow[i] = mnew;
      of[0][i] *= scale; of[1][i] *= scale; of[2][i] *= scale; of[3][i] *= scale;
    }
    __syncthreads();  // ensure P writes visible before PV reads (conservative)

    short8 ap0 = *(const short8*)&Ps[(wid * 16 + lr) * 72 + lg * 8];
    short8 ap1 = *(const short8*)&Ps[(wid * 16 + lr) * 72 + 32 + lg * 8];
#pragma unroll
    for (int df = 0; df < 4; df++) {
      short8 bv0 = *(const short8*)&Vs[(df * 16 + lr) * 72 + lg * 8];
      short8 bv1 = *(const short8*)&Vs[(df * 16 + lr) * 72 + 32 + lg * 8];
      of[df] = __builtin_amdgcn_mfma_f32_16x16x32_bf16(ap0, bv0, of[df], 0, 0, 0);
      of[df] = __builtin_amdgcn_mfma_f32_16x16x32_bf16(ap1, bv1, of[df], 0, 0, 0);
    }
    __syncthreads();
  }

  ushort* yp = ybf + (size_t)b * Tsz * Csz;
#pragma unroll
  for (int df = 0; df < 4; df++)
#pragma unroll
    for (int i = 0; i < 4; i++) {
      int qr = q0 + wid * 16 + 4 * lg + i;
      float v = of[df][i] / lrow[i];
      yp[(size_t)qr * Csz + h * 64 + df * 16 + lr] = f2bf(v);
    }
}

// ---------------- host ----------------
extern "C" void kernel_launch(void* const* d_in, const int* in_sizes, int n_in,
                              void* d_out, int out_size, void* d_ws, size_t ws_size,
                              hipStream_t stream) {
  (void)in_sizes; (void)n_in; (void)out_size;
  const int* idx      = (const int*)d_in[0];
  const float* wte    = (const float*)d_in[1];
  const float* wpe    = (const float*)d_in[2];
  const float* ln1_w  = (const float*)d_in[3];
  const float* ln1_b  = (const float*)d_in[4];
  const float* attn_w = (const float*)d_in[5];
  const float* attn_b = (const float*)d_in[6];
  const float* proj_w = (const float*)d_in[7];
  const float* proj_b = (const float*)d_in[8];
  const float* ln2_w  = (const float*)d_in[9];
  const float* ln2_b  = (const float*)d_in[10];
  const float* fc_w   = (const float*)d_in[11];
  const float* fc_b   = (const float*)d_in[12];
  const float* fc2_w  = (const float*)d_in[13];
  const float* fc2_b  = (const float*)d_in[14];
  const float* lnf_w  = (const float*)d_in[15];
  const float* lnf_b  = (const float*)d_in[16];
  const float* lm_w   = (const float*)d_in[17];
  float* out = (float*)d_out;

  char* ws = (char*)d_ws;
  float*  x     = (float*)(ws + 0);            // 2048*768*4   = 6291456
  ushort* qkvbf = (ushort*)(ws + 6291456);     // 2048*2304*2  = 9437184
  ushort* abuf  = (ushort*)(ws + 15728640);    // 2048*768*2   = 3145728
  ushort* hbuf  = (ushort*)(ws + 18874368);    // 2048*3072*2  = 12582912
  ushort* lmw   = (ushort*)(ws + 31457280);    // 50304*768*2  = 77266944
  ushort* wT    = (ushort*)(ws + 108724224);   // 12*C*C*2 per layer
  const size_t LSTRIDE = (size_t)12 * Csz * Csz;                 // elems per layer
  const size_t NEED_FULL = 108724224ull + LSTRIDE * 2 * Lsz;     // ~278.6 MB
  bool full = ws_size >= NEED_FULL;

  k_embed<<<Msz, 256, 0, stream>>>(idx, wte, wpe, x);
  k_f32_to_bf16_pad<<<4096, 256, 0, stream>>>(lm_w, lmw, Vsz * Csz, VPAD * Csz);
  if (full)
    k_prep<<<dim3(6912, Lsz), 256, 0, stream>>>(attn_w, proj_w, fc_w, fc2_w, wT, 0, LSTRIDE);

  for (int l = 0; l < Lsz; l++) {
    ushort* wTl = wT + (full ? (size_t)l * LSTRIDE : 0);
    if (!full)
      k_prep<<<dim3(6912, 1), 256, 0, stream>>>(attn_w, proj_w, fc_w, fc2_w, wTl, l, 0);
    const ushort* qkvW = wTl;
    const ushort* projW = wTl + (size_t)3 * Csz * Csz;
    const ushort* fcW   = wTl + (size_t)4 * Csz * Csz;
    const ushort* fc2W  = wTl + (size_t)8 * Csz * Csz;

    // --- attention ---
    k_ln<<<Msz, 256, 0, stream>>>(x, ln1_w + l * Csz, ln1_b + l * Csz, abuf);
    k_gemm<64, 128, 2, 4, 1, false><<<(Msz / 64) * (3 * Csz / 128), 256, 0, stream>>>(
        abuf, qkvW, attn_b + (size_t)l * 3 * Csz, nullptr, qkvbf, 3 * Csz, Csz, Msz / 64);
    k_attn<<<dim3(Tsz / 64, Bsz * Hsz), 256, 0, stream>>>(qkvbf, abuf);
    k_gemm<64, 64, 2, 2, 0, false><<<(Msz / 64) * (Csz / 64), 256, 0, stream>>>(
        abuf, projW, proj_b + (size_t)l * Csz, x, x, Csz, Csz, Msz / 64);
    // --- mlp ---
    k_ln<<<Msz, 256, 0, stream>>>(x, ln2_w + l * Csz, ln2_b + l * Csz, abuf);
    k_gemm<64, 128, 2, 4, 2, false><<<(Msz / 64) * (4 * Csz / 128), 256, 0, stream>>>(
        abuf, fcW, fc_b + (size_t)l * 4 * Csz, nullptr, hbuf, 4 * Csz, Csz, Msz / 64);
    k_gemm<64, 64, 2, 2, 0, false><<<(Msz / 64) * (Csz / 64), 256, 0, stream>>>(
        hbuf, fc2W, fc2_b + (size_t)l * Csz, x, x, Csz, 4 * Csz, Msz / 64);
  }

  k_ln<<<Msz, 256, 0, stream>>>(x, lnf_w, lnf_b, abuf);
  int ntm = Msz / 128;  // 16, m fastest
  k_gemm<128, 128, 4, 4, 0, true><<<ntm * (VPAD / 128), 256, 0, stream>>>(
      abuf, lmw, nullptr, nullptr, out, Vsz, Csz, ntm);
}